// Round 7
// baseline (483.085 us; speedup 1.0000x reference)
//
#include <hip/hip_runtime.h>

typedef unsigned short u16t;
typedef __bf16 bf16x8 __attribute__((ext_vector_type(8)));
typedef float f32x4 __attribute__((ext_vector_type(4)));
typedef float f32x16 __attribute__((ext_vector_type(16)));
typedef unsigned short ushort4_t __attribute__((ext_vector_type(4)));
typedef unsigned short ushort8_t __attribute__((ext_vector_type(8)));

#define B_    4
#define S_    2048
#define D_    2048
#define H_    16
#define KVH_  4
#define HD_   128
#define KDIM  2048
#define SCALE_ 0.08838834764831845f

__device__ __forceinline__ u16t f2bf(float f){
    unsigned u; __builtin_memcpy(&u, &f, 4);
    u += 0x7fffu + ((u >> 16) & 1u);
    return (u16t)(u >> 16);
}
__device__ __forceinline__ void glds16(const u16t* g, u16t* l){
    __builtin_amdgcn_global_load_lds((const __attribute__((address_space(1))) void*)g,
                                     (__attribute__((address_space(3))) void*)l, 16, 0, 0);
}
// Workgroup barrier WITHOUT the vmcnt(0) drain __syncthreads() would emit.
__device__ __forceinline__ void wg_barrier_lgkm(){
    __builtin_amdgcn_sched_barrier(0);
    asm volatile("s_waitcnt lgkmcnt(0)" ::: "memory");
    __builtin_amdgcn_s_barrier();
    __builtin_amdgcn_sched_barrier(0);
}
// Barrier gated on COUNTED vmcnt(8): waits the previous tile's 8 staging
// loads, leaves the just-issued 8 in flight (T3/T4 — never drain to 0).
__device__ __forceinline__ void wg_barrier_vm8(){
    __builtin_amdgcn_sched_barrier(0);
    asm volatile("s_waitcnt vmcnt(8)" ::: "memory");
    __builtin_amdgcn_s_barrier();
    __builtin_amdgcn_sched_barrier(0);
}
__device__ __forceinline__ unsigned cvt_pk_bf16(float lo, float hi){
    unsigned r;
    asm("v_cvt_pk_bf16_f32 %0, %1, %2" : "=v"(r) : "v"(lo), "v"(hi));
    return r;
}
__device__ __forceinline__ void permlane32_swap(unsigned &a, unsigned &b){
    asm volatile("v_permlane32_swap_b32 %0, %1" : "+v"(a), "+v"(b));
}

// ---------------- fp32 -> bf16 convert (x) ----------------
__global__ void f32_to_bf16(const float* __restrict__ in, u16t* __restrict__ out)
{
    int i = (blockIdx.x * 256 + threadIdx.x) * 4;
    float4 v = *(const float4*)(in + i);
    ushort4_t p;
    p[0] = f2bf(v.x); p[1] = f2bf(v.y); p[2] = f2bf(v.z); p[3] = f2bf(v.w);
    *(ushort4_t*)(out + i) = p;
}

// ---------- weight transpose+convert: W(K,N) fp32 -> Wt(N,K) bf16 ----------
__global__ void transpose_f32_bf16(const float* __restrict__ W, u16t* __restrict__ Wt,
                                   int Ncols, int Krows)
{
    __shared__ u16t tile[32][33];
    int tx = threadIdx.x, ty = threadIdx.y;
    int n = blockIdx.x * 32 + tx, k = blockIdx.y * 32 + ty;
    tile[ty][tx] = f2bf(W[(size_t)k * Ncols + n]);
    __syncthreads();
    int nn = blockIdx.x * 32 + ty, kk = blockIdx.y * 32 + tx;
    Wt[(size_t)nn * Krows + kk] = tile[tx][ty];
}

// ============ 256x256 GEMM core, BK=64, 8 waves, counted-vmcnt pipeline ======
// LDS: A/B tiles [256 rows][64 cols] bf16, double-buffered = 128 KB.
// T2 swizzle byte ^= ((row&7)<<4); staged via global_load_lds with LINEAR
// dest + inverse-swizzled per-lane SOURCE (rule #21).
// Ledger per K-tile t (p=t&1): frag-reads(t)+MFMA -> lgkm(0)+barrier ->
// issue 8 glds (t+2 -> buf p) -> vmcnt(8)+barrier (t+1 landed; t+2 in flight).
#define GEMM256_PROLOGUE_AND_KLOOP(GRIDX, NWG)                                    \
    __shared__ u16t As[2][256 * 64];                                              \
    __shared__ u16t Bs[2][256 * 64];                                              \
    const int tid  = threadIdx.x;                                                 \
    const int lane = tid & 63, w = tid >> 6;          /* wave 0..7 */             \
    const int wm = w >> 2, wn = w & 3;                                            \
    const int lr = lane & 15, quad = lane >> 4;                                   \
    const int sx = (lr & 7) << 4;                                                 \
    const int orig = blockIdx.y * (GRIDX) + blockIdx.x;                           \
    const int lin  = (orig & 7) * ((NWG) / 8) + (orig >> 3);                      \
    const int bxs  = lin % (GRIDX), bys = lin / (GRIDX);                          \
    const int m0 = bys * 256, n0 = bxs * 256;                                     \
    /* staging geometry: thread covers phys bytes (j*8+w)*1024 + lane*16 */       \
    const int rw = w * 8 + (lane >> 3);              /* row base (j=0) */         \
    const int ce = ((lane & 7) ^ (lane >> 3)) * 8;   /* inv-swz col elem */       \
    f32x4 acc[8][4];                                                              \
    _Pragma("unroll")                                                             \
    for (int r = 0; r < 8; r++)                                                   \
        _Pragma("unroll")                                                         \
        for (int c = 0; c < 4; c++) acc[r][c] = (f32x4){0.f, 0.f, 0.f, 0.f};      \
    /* prologue: stage tiles 0,1 ; vmcnt(8) leaves tile1 in flight */             \
    _Pragma("unroll")                                                             \
    for (int j = 0; j < 4; j++) {                                                 \
        glds16(A  + (size_t)(m0 + j * 64 + rw) * KDIM + ce,                       \
               &As[0][(j * 8 + w) * 512 + lane * 8]);                             \
        glds16(Bt + (size_t)(n0 + j * 64 + rw) * KDIM + ce,                       \
               &Bs[0][(j * 8 + w) * 512 + lane * 8]);                             \
    }                                                                             \
    _Pragma("unroll")                                                             \
    for (int j = 0; j < 4; j++) {                                                 \
        glds16(A  + (size_t)(m0 + j * 64 + rw) * KDIM + 64 + ce,                  \
               &As[1][(j * 8 + w) * 512 + lane * 8]);                             \
        glds16(Bt + (size_t)(n0 + j * 64 + rw) * KDIM + 64 + ce,                  \
               &Bs[1][(j * 8 + w) * 512 + lane * 8]);                             \
    }                                                                             \
    wg_barrier_vm8();                                                             \
    _Pragma("unroll 1")                                                           \
    for (int t = 0; t < KDIM / 64; t++) {                                         \
        const int p = t & 1;                                                      \
        const char* Ab = (const char*)&As[p][0];                                  \
        const char* Bb = (const char*)&Bs[p][0];                                  \
        bf16x8 bfr[4][2];                                                         \
        _Pragma("unroll")                                                         \
        for (int c = 0; c < 4; c++) {                                             \
            int Rb = (wn * 64 + c * 16 + lr) * 128;                               \
            bfr[c][0] = *(const bf16x8*)(Bb + ((Rb + quad * 16) ^ sx));           \
            bfr[c][1] = *(const bf16x8*)(Bb + ((Rb + 64 + quad * 16) ^ sx));      \
        }                                                                         \
        _Pragma("unroll")                                                         \
        for (int half = 0; half < 2; half++) {                                    \
            bf16x8 afr[4][2];                                                     \
            _Pragma("unroll")                                                     \
            for (int r = 0; r < 4; r++) {                                         \
                int Ra = (wm * 128 + (half * 4 + r) * 16 + lr) * 128;             \
                afr[r][0] = *(const bf16x8*)(Ab + ((Ra + quad * 16) ^ sx));       \
                afr[r][1] = *(const bf16x8*)(Ab + ((Ra + 64 + quad * 16) ^ sx));  \
            }                                                                     \
            __builtin_amdgcn_s_setprio(1);                                        \
            _Pragma("unroll")                                                     \
            for (int r = 0; r < 4; r++)                                           \
                _Pragma("unroll")                                                 \
                for (int c = 0; c < 4; c++) {                                     \
                    acc[half*4+r][c] = __builtin_amdgcn_mfma_f32_16x16x32_bf16(   \
                        afr[r][0], bfr[c][0], acc[half*4+r][c], 0, 0, 0);         \
                    acc[half*4+r][c] = __builtin_amdgcn_mfma_f32_16x16x32_bf16(   \
                        afr[r][1], bfr[c][1], acc[half*4+r][c], 0, 0, 0);         \
                }                                                                 \
            __builtin_amdgcn_s_setprio(0);                                        \
        }                                                                         \
        wg_barrier_lgkm();               /* all reads of buf p complete */        \
        const int tn = (t + 2 < KDIM / 64) ? (t + 2) : 0;  /* clamp: junk ok */   \
        const int kn = tn * 64;                                                   \
        _Pragma("unroll")                                                         \
        for (int j = 0; j < 4; j++) {                                             \
            glds16(A  + (size_t)(m0 + j * 64 + rw) * KDIM + kn + ce,              \
                   &As[p][(j * 8 + w) * 512 + lane * 8]);                         \
            glds16(Bt + (size_t)(n0 + j * 64 + rw) * KDIM + kn + ce,              \
                   &Bs[p][(j * 8 + w) * 512 + lane * 8]);                         \
        }                                                                         \
        wg_barrier_vm8();                /* tile t+1 resident; t+2 in flight */   \
    }

// ---------------- O-projection GEMM: fp32 store to d_out ----------------
__global__ __launch_bounds__(512, 2) void
gemm_o(const u16t* __restrict__ A, const u16t* __restrict__ Bt,
       const float* __restrict__ bias, float* __restrict__ out)
{
    GEMM256_PROLOGUE_AND_KLOOP(8, 256)
#pragma unroll
    for (int r = 0; r < 8; r++) {
#pragma unroll
        for (int c = 0; c < 4; c++) {
            int n = n0 + wn * 64 + c * 16 + lr;
            float bval = bias[n];
#pragma unroll
            for (int g = 0; g < 4; g++) {
                int m = m0 + wm * 128 + r * 16 + quad * 4 + g;
                out[(size_t)m * D_ + n] = acc[r][c][g] + bval;
            }
        }
    }
}

// ---------------- fused QKV GEMM over N=3072 (Bt = [Wqt;Wkt;Wvt]) ------------
// 256-wide n-tiles: tiles 0-7 = Q, 8-9 = K, 10-11 = V (region uniform per tile)
__global__ __launch_bounds__(512, 2) void
gemm_qkv(const u16t* __restrict__ A, const u16t* __restrict__ Bt,
         const float* __restrict__ bq, const float* __restrict__ bk,
         const float* __restrict__ bv,
         u16t* __restrict__ q_t, u16t* __restrict__ k_t,
         u16t* __restrict__ v_t,
         const float* __restrict__ fc, const float* __restrict__ fs)
{
    GEMM256_PROLOGUE_AND_KLOOP(12, 384)
    const int region = (bxs < 8) ? 0 : ((bxs < 10) ? 1 : 2);
#pragma unroll
    for (int r = 0; r < 8; r++) {
#pragma unroll
        for (int c = 0; c < 4; c++) {
            int n = n0 + wn * 64 + c * 16 + lr;
            if (region == 0) {          // Q + RoPE
                float bval = bq[n];
                int hh = n >> 7, d = n & 127, i2 = d >> 1;
#pragma unroll
                for (int g = 0; g < 4; g++) {
                    int m = m0 + wm * 128 + r * 16 + quad * 4 + g;
                    int bb = m >> 11, s = m & (S_ - 1);
                    float v = acc[r][c][g] + bval;
                    float p = __shfl_xor(v, 1);
                    float cf = fc[s * 64 + i2], sf = fs[s * 64 + i2];
                    float o = (d & 1) ? (p * sf + v * cf) : (v * cf - p * sf);
                    q_t[(((size_t)bb * H_ + hh) * S_ + s) * HD_ + d] = f2bf(o);
                }
            } else if (region == 1) {   // K + RoPE
                int nk = n - 2048;
                float bval = bk[nk];
                int hh = nk >> 7, d = nk & 127, i2 = d >> 1;
#pragma unroll
                for (int g = 0; g < 4; g++) {
                    int m = m0 + wm * 128 + r * 16 + quad * 4 + g;
                    int bb = m >> 11, s = m & (S_ - 1);
                    float v = acc[r][c][g] + bval;
                    float p = __shfl_xor(v, 1);
                    float cf = fc[s * 64 + i2], sf = fs[s * 64 + i2];
                    float o = (d & 1) ? (p * sf + v * cf) : (v * cf - p * sf);
                    k_t[(((size_t)bb * KVH_ + hh) * S_ + s) * HD_ + d] = f2bf(o);
                }
            } else {                    // V transposed
                int nv = n - 2560;
                float bval = bv[nv];
                int kv = nv >> 7, d = nv & 127;
                int mb = m0 + wm * 128 + r * 16 + quad * 4;
                int bb = mb >> 11, s = mb & (S_ - 1);
                ushort4_t pk;
#pragma unroll
                for (int g = 0; g < 4; g++) pk[g] = f2bf(acc[r][c][g] + bval);
                *(ushort4_t*)(v_t + (((size_t)bb * KVH_ + kv) * HD_ + d) * S_ + s) = pk;
            }
        }
    }
}

// ---------------- flash attention, causal, GQA (bf16 in/out) ----------------
// 4 waves x 32 q-rows, 32x32x16 MFMA, swapped QK^T, in-register P (cvt_pk +
// permlane32_swap), XOR-swizzled K/V LDS, reg-staged double buffer,
// lgkm-only barrier. q-tile PAIRING for perfect causal balance.
__global__ __launch_bounds__(256, 2) void
attn_kernel(const u16t* __restrict__ qt, const u16t* __restrict__ kt,
            const u16t* __restrict__ vt, u16t* __restrict__ att)
{
    __shared__ char Ks[2][8192];
    __shared__ char Vs[2][8192];
    const int tid  = threadIdx.x;
    const int lane = tid & 63, w = tid >> 6;          // w 0..3
    const int l5 = lane & 31, hi = lane >> 5;
    const int bh = blockIdx.y, b = bh >> 4, h = bh & 15, kv = h >> 2;
    const int bx = blockIdx.x;                        // 0..7

    const u16t* kb = kt + ((size_t)b * KVH_ + kv) * S_ * HD_;
    const u16t* vb = vt + ((size_t)b * KVH_ + kv) * HD_ * S_;

    f32x16 zero16;
#pragma unroll
    for (int j = 0; j < 16; j++) zero16[j] = 0.f;

    const int krow = tid >> 4, kcol = tid & 15;   // K: 32 rows x 16 col-chunks
    const int vd   = tid >> 2, vcol = tid & 3;    // V^T: 128 rows x 4 t-chunks
    const int kw0 = ((krow     ) * 256 + kcol * 16) ^ ((krow & 7) << 4);
    const int kw1 = ((krow + 16) * 256 + kcol * 16) ^ ((krow & 7) << 4);
    const int vw0 = ((vd      ) * 64 + vcol * 16) ^ (((vd >> 1) & 3) << 5);
    const int vw1 = ((vd + 64 ) * 64 + vcol * 16) ^ (((vd >> 1) & 3) << 5);

    ushort8_t kr[2][2], vr[2][2];

#pragma unroll 1
    for (int seg = 0; seg < 2; seg++) {
        const int q0 = (seg == 0 ? (15 - bx) : bx) * 128;   // heavy tile first
        const u16t* qb = qt + (((size_t)b * H_ + h) * S_ + q0) * HD_;

        bf16x8 qa[8];
#pragma unroll
        for (int ks = 0; ks < 8; ks++)
            qa[ks] = *(const bf16x8*)(qb + (w * 32 + l5) * HD_ + ks * 16 + hi * 8);

        f32x16 o[4];
#pragma unroll
        for (int i = 0; i < 4; i++) o[i] = zero16;
        float lpart = 0.f;

        const int ntile = q0 / 32 + 4;   // even
#pragma unroll
        for (int p = 0; p < 2; p++) {
            int t0 = p * 32;
            kr[p][0] = *(const ushort8_t*)(kb + (size_t)(t0 + krow     ) * HD_ + kcol * 8);
            kr[p][1] = *(const ushort8_t*)(kb + (size_t)(t0 + krow + 16) * HD_ + kcol * 8);
            vr[p][0] = *(const ushort8_t*)(vb + (size_t)(vd     ) * S_ + t0 + vcol * 8);
            vr[p][1] = *(const ushort8_t*)(vb + (size_t)(vd + 64) * S_ + t0 + vcol * 8);
        }

        for (int it = 0; it < ntile; it += 2) {
#pragma unroll
            for (int p = 0; p < 2; p++) {
                const int t0 = (it + p) * 32;
                *(ushort8_t*)(Ks[p] + kw0) = kr[p][0];
                *(ushort8_t*)(Ks[p] + kw1) = kr[p][1];
                *(ushort8_t*)(Vs[p] + vw0) = vr[p][0];
                *(ushort8_t*)(Vs[p] + vw1) = vr[p][1];
                const int tn0 = (it + p + 2 < ntile) ? (it + p + 2) * 32 : 0;
                kr[p][0] = *(const ushort8_t*)(kb + (size_t)(tn0 + krow     ) * HD_ + kcol * 8);
                kr[p][1] = *(const ushort8_t*)(kb + (size_t)(tn0 + krow + 16) * HD_ + kcol * 8);
                vr[p][0] = *(const ushort8_t*)(vb + (size_t)(vd     ) * S_ + tn0 + vcol * 8);
                vr[p][1] = *(const ushort8_t*)(vb + (size_t)(vd + 64) * S_ + tn0 + vcol * 8);
                wg_barrier_lgkm();   // LDS visible; global prefetch stays in flight

                if (t0 > q0 + w * 32 + 31) continue;   // tile fully masked for this wave

                f32x16 sa = zero16, sb = zero16;
                __builtin_amdgcn_s_setprio(1);
#pragma unroll
                for (int ks = 0; ks < 8; ks += 2) {
                    bf16x8 kf0 = *(const bf16x8*)(Ks[p] +
                        ((l5 * 256 + ks * 32 + hi * 16) ^ ((l5 & 7) << 4)));
                    sa = __builtin_amdgcn_mfma_f32_32x32x16_bf16(kf0, qa[ks], sa, 0, 0, 0);
                    bf16x8 kf1 = *(const bf16x8*)(Ks[p] +
                        ((l5 * 256 + (ks + 1) * 32 + hi * 16) ^ ((l5 & 7) << 4)));
                    sb = __builtin_amdgcn_mfma_f32_32x32x16_bf16(kf1, qa[ks + 1], sb, 0, 0, 0);
                }
                __builtin_amdgcn_s_setprio(0);
                f32x16 sc = sa + sb;

                float pr[16];
                if (t0 + 31 <= q0 + w * 32) {            // fully unmasked for this wave
#pragma unroll
                    for (int r = 0; r < 16; r++) pr[r] = __expf(sc[r] * SCALE_);
                } else {
                    const int srow = q0 + w * 32 + l5;
#pragma unroll
                    for (int r = 0; r < 16; r++) {
                        int tc = t0 + (r & 3) + 8 * (r >> 2) + 4 * hi;
                        pr[r] = __expf(sc[r] * SCALE_ + ((tc > srow) ? -1e9f : 0.f));
                    }
                }
#pragma unroll
                for (int r = 0; r < 16; r++) lpart += pr[r];

                unsigned d0[4], d1[4];
#pragma unroll
                for (int q4 = 0; q4 < 4; q4++) {
                    d0[q4] = cvt_pk_bf16(pr[4 * q4 + 0], pr[4 * q4 + 1]);
                    d1[q4] = cvt_pk_bf16(pr[4 * q4 + 2], pr[4 * q4 + 3]);
                }
                permlane32_swap(d0[0], d0[1]);
                permlane32_swap(d1[0], d1[1]);
                permlane32_swap(d0[2], d0[3]);
                permlane32_swap(d1[2], d1[3]);
                union { unsigned u[4]; bf16x8 v; } pa0, pa1;
                pa0.u[0] = d0[0]; pa0.u[1] = d1[0]; pa0.u[2] = d0[1]; pa0.u[3] = d1[1];
                pa1.u[0] = d0[2]; pa1.u[1] = d1[2]; pa1.u[2] = d0[3]; pa1.u[3] = d1[3];

                __builtin_amdgcn_s_setprio(1);
#pragma unroll
                for (int dt = 0; dt < 4; dt++) {
                    bf16x8 vf0 = *(const bf16x8*)(Vs[p] +
                        (((dt * 32 + l5) * 64 + hi * 16) ^ (((l5 >> 1) & 3) << 5)));
                    o[dt] = __builtin_amdgcn_mfma_f32_32x32x16_bf16(pa0.v, vf0, o[dt], 0, 0, 0);
                    bf16x8 vf1 = *(const bf16x8*)(Vs[p] +
                        (((dt * 32 + l5) * 64 + 32 + hi * 16) ^ (((l5 >> 1) & 3) << 5)));
                    o[dt] = __builtin_amdgcn_mfma_f32_32x32x16_bf16(pa1.v, vf1, o[dt], 0, 0, 0);
                }
                __builtin_amdgcn_s_setprio(0);
            }
        }

        float lf = lpart + __shfl_xor(lpart, 32);
        float linv = 1.f / lf;
#pragma unroll
        for (int r = 0; r < 16; r++) {
            int qrow = (r & 3) + 8 * (r >> 2) + 4 * hi;
            float iv = __shfl(linv, qrow);
            int s = q0 + w * 32 + qrow;
            u16t* orow = att + ((size_t)(b * S_ + s)) * D_ + h * HD_ + l5;
#pragma unroll
            for (int dt = 0; dt < 4; dt++)
                orow[dt * 32] = f2bf(o[dt][r] * iv);
        }
    }
}

extern "C" void kernel_launch(void* const* d_in, const int* in_sizes, int n_in,
                              void* d_out, int out_size, void* d_ws, size_t ws_size,
                              hipStream_t stream)
{
    const float* x  = (const float*)d_in[0];
    const float* Wq = (const float*)d_in[1];
    const float* bq = (const float*)d_in[2];
    const float* Wk = (const float*)d_in[3];
    const float* bk = (const float*)d_in[4];
    const float* Wv = (const float*)d_in[5];
    const float* bv = (const float*)d_in[6];
    const float* Wo = (const float*)d_in[7];
    const float* bo = (const float*)d_in[8];
    const float* fc = (const float*)d_in[9];
    const float* fs = (const float*)d_in[10];
    // d_in[11] (mask): fixed causal mask, analytic. d_in[12] (start_pos): 0.

    const size_t M1 = (size_t)1024 * 1024;
    u16t* ws   = (u16t*)d_ws;
    u16t* x_bf = ws;
    u16t* att  = ws;
    u16t* Wqt  = ws + 16 * M1;
    u16t* Wot  = ws + 16 * M1;
    u16t* Wkt  = ws + 20 * M1;
    u16t* Wvt  = ws + 21 * M1;
    u16t* k_t  = ws + 22 * M1;
    u16t* v_t  = ws + 26 * M1;
    u16t* q_t  = (u16t*)d_out;

    f32_to_bf16<<<dim3(16384), 256, 0, stream>>>(x, x_bf);

    dim3 tb(32, 32);
    transpose_f32_bf16<<<dim3(64, 64), tb, 0, stream>>>(Wq, Wqt, 2048, 2048);
    transpose_f32_bf16<<<dim3(16, 64), tb, 0, stream>>>(Wk, Wkt, 512, 2048);
    transpose_f32_bf16<<<dim3(16, 64), tb, 0, stream>>>(Wv, Wvt, 512, 2048);

    gemm_qkv<<<dim3(12, 32), 512, 0, stream>>>(x_bf, Wqt, bq, bk, bv,
                                               q_t, k_t, v_t, fc, fs);

    attn_kernel<<<dim3(8, 64), 256, 0, stream>>>(q_t, k_t, v_t, att);

    transpose_f32_bf16<<<dim3(64, 64), tb, 0, stream>>>(Wo, Wot, 2048, 2048);

    gemm_o<<<dim3(8, 32), 512, 0, stream>>>(att, Wot, bo, (float*)d_out);
}

// Round 8
// 465.871 us; speedup vs baseline: 1.0370x; 1.0370x over previous
//
#include <hip/hip_runtime.h>

typedef unsigned short u16t;
typedef __bf16 bf16x8 __attribute__((ext_vector_type(8)));
typedef float f32x4 __attribute__((ext_vector_type(4)));
typedef float f32x16 __attribute__((ext_vector_type(16)));
typedef unsigned short ushort4_t __attribute__((ext_vector_type(4)));
typedef unsigned short ushort8_t __attribute__((ext_vector_type(8)));

#define B_    4
#define S_    2048
#define D_    2048
#define H_    16
#define KVH_  4
#define HD_   128
#define KDIM  2048
#define SCALE_ 0.08838834764831845f

__device__ __forceinline__ u16t f2bf(float f){
    unsigned u; __builtin_memcpy(&u, &f, 4);
    u += 0x7fffu + ((u >> 16) & 1u);
    return (u16t)(u >> 16);
}
__device__ __forceinline__ void glds16(const u16t* g, u16t* l){
    __builtin_amdgcn_global_load_lds((const __attribute__((address_space(1))) void*)g,
                                     (__attribute__((address_space(3))) void*)l, 16, 0, 0);
}
// Workgroup barrier WITHOUT the vmcnt(0) drain __syncthreads() would emit.
__device__ __forceinline__ void wg_barrier_lgkm(){
    __builtin_amdgcn_sched_barrier(0);
    asm volatile("s_waitcnt lgkmcnt(0)" ::: "memory");
    __builtin_amdgcn_s_barrier();
    __builtin_amdgcn_sched_barrier(0);
}
// Barrier gated on vmcnt(0): used where staged loads were ISSUED a full
// compute-phase earlier (T3 stage-early recipe) so the wait is ~free.
__device__ __forceinline__ void wg_barrier_vm0(){
    __builtin_amdgcn_sched_barrier(0);
    asm volatile("s_waitcnt vmcnt(0)" ::: "memory");
    __builtin_amdgcn_s_barrier();
    __builtin_amdgcn_sched_barrier(0);
}
__device__ __forceinline__ unsigned cvt_pk_bf16(float lo, float hi){
    unsigned r;
    asm("v_cvt_pk_bf16_f32 %0, %1, %2" : "=v"(r) : "v"(lo), "v"(hi));
    return r;
}
__device__ __forceinline__ void permlane32_swap(unsigned &a, unsigned &b){
    asm volatile("v_permlane32_swap_b32 %0, %1" : "+v"(a), "+v"(b));
}

// ---------------- fp32 -> bf16 convert (x) ----------------
__global__ void f32_to_bf16(const float* __restrict__ in, u16t* __restrict__ out)
{
    int i = (blockIdx.x * 256 + threadIdx.x) * 4;
    float4 v = *(const float4*)(in + i);
    ushort4_t p;
    p[0] = f2bf(v.x); p[1] = f2bf(v.y); p[2] = f2bf(v.z); p[3] = f2bf(v.w);
    *(ushort4_t*)(out + i) = p;
}

// ---------- weight transpose+convert: W(K,N) fp32 -> Wt(N,K) bf16 ----------
__global__ void transpose_f32_bf16(const float* __restrict__ W, u16t* __restrict__ Wt,
                                   int Ncols, int Krows)
{
    __shared__ u16t tile[32][33];
    int tx = threadIdx.x, ty = threadIdx.y;
    int n = blockIdx.x * 32 + tx, k = blockIdx.y * 32 + ty;
    tile[ty][tx] = f2bf(W[(size_t)k * Ncols + n]);
    __syncthreads();
    int nn = blockIdx.x * 32 + ty, kk = blockIdx.y * 32 + tx;
    Wt[(size_t)nn * Krows + kk] = tile[tx][ty];
}

// ============ 128x128 GEMM core, BK=64, double-buffered, stage-early =========
// LDS: A/B [128 rows][64 cols] bf16 x 2 buffers = 64 KB -> 2 blocks/CU.
// Conflict-free: LDS[row][chunk] holds global col-chunk (chunk ^ (row&7));
// staged via global_load_lds with LINEAR dest + inverse-permuted SOURCE
// column (rule #21, measured 0 conflicts in r7); reads XOR the same mask.
// Schedule (T3 minimum-2-phase): per K-tile t -- issue 8 glds for t+1 into
// buf p^1 FIRST, then ds_read+MFMA tile t from buf p, then vmcnt(0)+barrier
// (the staged loads had the whole MFMA phase to land; no mid-loop drain).
#define GEMM128_CORE(GRIDX, NWG)                                                  \
    __shared__ u16t As[2][128 * 64];                                              \
    __shared__ u16t Bs[2][128 * 64];                                              \
    const int tid  = threadIdx.x;                                                 \
    const int lane = tid & 63, w = tid >> 6;                                      \
    const int wr = (w >> 1) * 64, wc = (w & 1) * 64;                              \
    const int lr = lane & 15, quad = lane >> 4;                                   \
    const int sxr = lr & 7;                       /* read-side swizzle bits */    \
    const int orig = blockIdx.y * (GRIDX) + blockIdx.x;                           \
    const int lin  = (orig & 7) * ((NWG) / 8) + (orig >> 3);                      \
    const int bxs  = lin % (GRIDX), bys = lin / (GRIDX);                          \
    const int m0 = bys * 128, n0 = bxs * 128;                                     \
    /* staging: issue j covers granule G=j*256+tid; row=G>>3, dest linear;  */    \
    /* source col-chunk = (G&7)^(row&7) -> constant across j               */     \
    const int srow = tid >> 3;                                                    \
    const int sko  = (((tid & 7) ^ ((tid >> 3) & 7)) << 3);                       \
    f32x4 acc[4][4];                                                              \
    _Pragma("unroll")                                                             \
    for (int r = 0; r < 4; r++)                                                   \
        _Pragma("unroll")                                                         \
        for (int c = 0; c < 4; c++) acc[r][c] = (f32x4){0.f, 0.f, 0.f, 0.f};      \
    _Pragma("unroll")                                                             \
    for (int j = 0; j < 4; j++) {                                                 \
        glds16(A  + (size_t)(m0 + j * 32 + srow) * KDIM + sko,                    \
               &As[0][(j * 256 + tid) * 8]);                                      \
        glds16(Bt + (size_t)(n0 + j * 32 + srow) * KDIM + sko,                    \
               &Bs[0][(j * 256 + tid) * 8]);                                      \
    }                                                                             \
    wg_barrier_vm0();                                                             \
    _Pragma("unroll 1")                                                           \
    for (int t = 0; t < KDIM / 64; t++) {                                         \
        const int p = t & 1;                                                      \
        const int kn = ((t + 1 < KDIM / 64) ? (t + 1) : (KDIM / 64 - 1)) * 64;    \
        _Pragma("unroll")                                                         \
        for (int j = 0; j < 4; j++) {                                             \
            glds16(A  + (size_t)(m0 + j * 32 + srow) * KDIM + kn + sko,           \
                   &As[p ^ 1][(j * 256 + tid) * 8]);                              \
            glds16(Bt + (size_t)(n0 + j * 32 + srow) * KDIM + kn + sko,           \
                   &Bs[p ^ 1][(j * 256 + tid) * 8]);                              \
        }                                                                         \
        __builtin_amdgcn_sched_barrier(0);                                        \
        _Pragma("unroll")                                                         \
        for (int half = 0; half < 2; half++) {                                    \
            bf16x8 a[4], b[4];                                                    \
            _Pragma("unroll")                                                     \
            for (int r = 0; r < 4; r++) {                                         \
                int row = wr + r * 16 + lr;                                       \
                a[r] = *(const bf16x8*)(&As[p][row * 64 +                         \
                          (((half * 4 + quad) ^ sxr) << 3)]);                     \
            }                                                                     \
            _Pragma("unroll")                                                     \
            for (int c = 0; c < 4; c++) {                                         \
                int row = wc + c * 16 + lr;                                       \
                b[c] = *(const bf16x8*)(&Bs[p][row * 64 +                         \
                          (((half * 4 + quad) ^ sxr) << 3)]);                     \
            }                                                                     \
            __builtin_amdgcn_s_setprio(1);                                        \
            _Pragma("unroll")                                                     \
            for (int r = 0; r < 4; r++)                                           \
                _Pragma("unroll")                                                 \
                for (int c = 0; c < 4; c++)                                       \
                    acc[r][c] = __builtin_amdgcn_mfma_f32_16x16x32_bf16(          \
                        a[r], b[c], acc[r][c], 0, 0, 0);                          \
            __builtin_amdgcn_s_setprio(0);                                        \
        }                                                                         \
        wg_barrier_vm0();                                                         \
    }

// ---------------- O-projection GEMM: fp32 store to d_out ----------------
__global__ __launch_bounds__(256) void
gemm_o(const u16t* __restrict__ A, const u16t* __restrict__ Bt,
       const float* __restrict__ bias, float* __restrict__ out)
{
    GEMM128_CORE(16, 1024)
#pragma unroll
    for (int r = 0; r < 4; r++) {
#pragma unroll
        for (int c = 0; c < 4; c++) {
            int n = n0 + wc + c * 16 + lr;
            float bval = bias[n];
#pragma unroll
            for (int g = 0; g < 4; g++) {
                int m = m0 + wr + r * 16 + quad * 4 + g;
                out[(size_t)m * D_ + n] = acc[r][c][g] + bval;
            }
        }
    }
}

// ---------------- fused QKV GEMM over N=3072 (Bt = [Wqt;Wkt;Wvt]) ------------
__global__ __launch_bounds__(256) void
gemm_qkv(const u16t* __restrict__ A, const u16t* __restrict__ Bt,
         const float* __restrict__ bq, const float* __restrict__ bk,
         const float* __restrict__ bv,
         u16t* __restrict__ q_t, u16t* __restrict__ k_t,
         u16t* __restrict__ v_t,
         const float* __restrict__ fc, const float* __restrict__ fs)
{
    GEMM128_CORE(24, 1536)
    const int region = (bxs < 16) ? 0 : ((bxs < 20) ? 1 : 2);
#pragma unroll
    for (int r = 0; r < 4; r++) {
#pragma unroll
        for (int c = 0; c < 4; c++) {
            int n = n0 + wc + c * 16 + lr;
            if (region == 0) {          // Q + RoPE
                float bval = bq[n];
                int hh = n >> 7, d = n & 127, i2 = d >> 1;
#pragma unroll
                for (int g = 0; g < 4; g++) {
                    int m = m0 + wr + r * 16 + quad * 4 + g;
                    int bb = m >> 11, s = m & (S_ - 1);
                    float v = acc[r][c][g] + bval;
                    float p = __shfl_xor(v, 1);
                    float cf = fc[s * 64 + i2], sf = fs[s * 64 + i2];
                    float o = (d & 1) ? (p * sf + v * cf) : (v * cf - p * sf);
                    q_t[(((size_t)bb * H_ + hh) * S_ + s) * HD_ + d] = f2bf(o);
                }
            } else if (region == 1) {   // K + RoPE
                int nk = n - 2048;
                float bval = bk[nk];
                int hh = nk >> 7, d = nk & 127, i2 = d >> 1;
#pragma unroll
                for (int g = 0; g < 4; g++) {
                    int m = m0 + wr + r * 16 + quad * 4 + g;
                    int bb = m >> 11, s = m & (S_ - 1);
                    float v = acc[r][c][g] + bval;
                    float p = __shfl_xor(v, 1);
                    float cf = fc[s * 64 + i2], sf = fs[s * 64 + i2];
                    float o = (d & 1) ? (p * sf + v * cf) : (v * cf - p * sf);
                    k_t[(((size_t)bb * KVH_ + hh) * S_ + s) * HD_ + d] = f2bf(o);
                }
            } else {                    // V transposed
                int nv = n - 2560;
                float bval = bv[nv];
                int kv = nv >> 7, d = nv & 127;
                int mb = m0 + wr + r * 16 + quad * 4;
                int bb = mb >> 11, s = mb & (S_ - 1);
                ushort4_t pk;
#pragma unroll
                for (int g = 0; g < 4; g++) pk[g] = f2bf(acc[r][c][g] + bval);
                *(ushort4_t*)(v_t + (((size_t)bb * KVH_ + kv) * HD_ + d) * S_ + s) = pk;
            }
        }
    }
}

// ---------------- flash attention, causal, GQA (bf16 in/out) ----------------
// 4 waves x 32 q-rows, 32x32x16 MFMA, swapped QK^T, in-register P (cvt_pk +
// permlane32_swap), XOR-swizzled K/V LDS, reg-staged double buffer,
// lgkm-only barrier. q-tile PAIRING for perfect causal balance.
__global__ __launch_bounds__(256, 2) void
attn_kernel(const u16t* __restrict__ qt, const u16t* __restrict__ kt,
            const u16t* __restrict__ vt, u16t* __restrict__ att)
{
    __shared__ char Ks[2][8192];
    __shared__ char Vs[2][8192];
    const int tid  = threadIdx.x;
    const int lane = tid & 63, w = tid >> 6;          // w 0..3
    const int l5 = lane & 31, hi = lane >> 5;
    const int bh = blockIdx.y, b = bh >> 4, h = bh & 15, kv = h >> 2;
    const int bx = blockIdx.x;                        // 0..7

    const u16t* kb = kt + ((size_t)b * KVH_ + kv) * S_ * HD_;
    const u16t* vb = vt + ((size_t)b * KVH_ + kv) * HD_ * S_;

    f32x16 zero16;
#pragma unroll
    for (int j = 0; j < 16; j++) zero16[j] = 0.f;

    const int krow = tid >> 4, kcol = tid & 15;   // K: 32 rows x 16 col-chunks
    const int vd   = tid >> 2, vcol = tid & 3;    // V^T: 128 rows x 4 t-chunks
    const int kw0 = ((krow     ) * 256 + kcol * 16) ^ ((krow & 7) << 4);
    const int kw1 = ((krow + 16) * 256 + kcol * 16) ^ ((krow & 7) << 4);
    const int vw0 = ((vd      ) * 64 + vcol * 16) ^ (((vd >> 1) & 3) << 5);
    const int vw1 = ((vd + 64 ) * 64 + vcol * 16) ^ (((vd >> 1) & 3) << 5);

    ushort8_t kr[2][2], vr[2][2];

#pragma unroll 1
    for (int seg = 0; seg < 2; seg++) {
        const int q0 = (seg == 0 ? (15 - bx) : bx) * 128;   // heavy tile first
        const u16t* qb = qt + (((size_t)b * H_ + h) * S_ + q0) * HD_;

        bf16x8 qa[8];
#pragma unroll
        for (int ks = 0; ks < 8; ks++)
            qa[ks] = *(const bf16x8*)(qb + (w * 32 + l5) * HD_ + ks * 16 + hi * 8);

        f32x16 o[4];
#pragma unroll
        for (int i = 0; i < 4; i++) o[i] = zero16;
        float lpart = 0.f;

        const int ntile = q0 / 32 + 4;   // even
#pragma unroll
        for (int p = 0; p < 2; p++) {
            int t0 = p * 32;
            kr[p][0] = *(const ushort8_t*)(kb + (size_t)(t0 + krow     ) * HD_ + kcol * 8);
            kr[p][1] = *(const ushort8_t*)(kb + (size_t)(t0 + krow + 16) * HD_ + kcol * 8);
            vr[p][0] = *(const ushort8_t*)(vb + (size_t)(vd     ) * S_ + t0 + vcol * 8);
            vr[p][1] = *(const ushort8_t*)(vb + (size_t)(vd + 64) * S_ + t0 + vcol * 8);
        }

        for (int it = 0; it < ntile; it += 2) {
#pragma unroll
            for (int p = 0; p < 2; p++) {
                const int t0 = (it + p) * 32;
                *(ushort8_t*)(Ks[p] + kw0) = kr[p][0];
                *(ushort8_t*)(Ks[p] + kw1) = kr[p][1];
                *(ushort8_t*)(Vs[p] + vw0) = vr[p][0];
                *(ushort8_t*)(Vs[p] + vw1) = vr[p][1];
                const int tn0 = (it + p + 2 < ntile) ? (it + p + 2) * 32 : 0;
                kr[p][0] = *(const ushort8_t*)(kb + (size_t)(tn0 + krow     ) * HD_ + kcol * 8);
                kr[p][1] = *(const ushort8_t*)(kb + (size_t)(tn0 + krow + 16) * HD_ + kcol * 8);
                vr[p][0] = *(const ushort8_t*)(vb + (size_t)(vd     ) * S_ + tn0 + vcol * 8);
                vr[p][1] = *(const ushort8_t*)(vb + (size_t)(vd + 64) * S_ + tn0 + vcol * 8);
                wg_barrier_lgkm();   // LDS visible; global prefetch stays in flight

                if (t0 > q0 + w * 32 + 31) continue;   // tile fully masked for this wave

                f32x16 sa = zero16, sb = zero16;
                __builtin_amdgcn_s_setprio(1);
#pragma unroll
                for (int ks = 0; ks < 8; ks += 2) {
                    bf16x8 kf0 = *(const bf16x8*)(Ks[p] +
                        ((l5 * 256 + ks * 32 + hi * 16) ^ ((l5 & 7) << 4)));
                    sa = __builtin_amdgcn_mfma_f32_32x32x16_bf16(kf0, qa[ks], sa, 0, 0, 0);
                    bf16x8 kf1 = *(const bf16x8*)(Ks[p] +
                        ((l5 * 256 + (ks + 1) * 32 + hi * 16) ^ ((l5 & 7) << 4)));
                    sb = __builtin_amdgcn_mfma_f32_32x32x16_bf16(kf1, qa[ks + 1], sb, 0, 0, 0);
                }
                __builtin_amdgcn_s_setprio(0);
                f32x16 sc = sa + sb;

                float pr[16];
                if (t0 + 31 <= q0 + w * 32) {            // fully unmasked for this wave
#pragma unroll
                    for (int r = 0; r < 16; r++) pr[r] = __expf(sc[r] * SCALE_);
                } else {
                    const int srow2 = q0 + w * 32 + l5;
#pragma unroll
                    for (int r = 0; r < 16; r++) {
                        int tc = t0 + (r & 3) + 8 * (r >> 2) + 4 * hi;
                        pr[r] = __expf(sc[r] * SCALE_ + ((tc > srow2) ? -1e9f : 0.f));
                    }
                }
#pragma unroll
                for (int r = 0; r < 16; r++) lpart += pr[r];

                unsigned d0[4], d1[4];
#pragma unroll
                for (int q4 = 0; q4 < 4; q4++) {
                    d0[q4] = cvt_pk_bf16(pr[4 * q4 + 0], pr[4 * q4 + 1]);
                    d1[q4] = cvt_pk_bf16(pr[4 * q4 + 2], pr[4 * q4 + 3]);
                }
                permlane32_swap(d0[0], d0[1]);
                permlane32_swap(d1[0], d1[1]);
                permlane32_swap(d0[2], d0[3]);
                permlane32_swap(d1[2], d1[3]);
                union { unsigned u[4]; bf16x8 v; } pa0, pa1;
                pa0.u[0] = d0[0]; pa0.u[1] = d1[0]; pa0.u[2] = d0[1]; pa0.u[3] = d1[1];
                pa1.u[0] = d0[2]; pa1.u[1] = d1[2]; pa1.u[2] = d0[3]; pa1.u[3] = d1[3];

                __builtin_amdgcn_s_setprio(1);
#pragma unroll
                for (int dt = 0; dt < 4; dt++) {
                    bf16x8 vf0 = *(const bf16x8*)(Vs[p] +
                        (((dt * 32 + l5) * 64 + hi * 16) ^ (((l5 >> 1) & 3) << 5)));
                    o[dt] = __builtin_amdgcn_mfma_f32_32x32x16_bf16(pa0.v, vf0, o[dt], 0, 0, 0);
                    bf16x8 vf1 = *(const bf16x8*)(Vs[p] +
                        (((dt * 32 + l5) * 64 + 32 + hi * 16) ^ (((l5 >> 1) & 3) << 5)));
                    o[dt] = __builtin_amdgcn_mfma_f32_32x32x16_bf16(pa1.v, vf1, o[dt], 0, 0, 0);
                }
                __builtin_amdgcn_s_setprio(0);
            }
        }

        float lf = lpart + __shfl_xor(lpart, 32);
        float linv = 1.f / lf;
#pragma unroll
        for (int r = 0; r < 16; r++) {
            int qrow = (r & 3) + 8 * (r >> 2) + 4 * hi;
            float iv = __shfl(linv, qrow);
            int s = q0 + w * 32 + qrow;
            u16t* orow = att + ((size_t)(b * S_ + s)) * D_ + h * HD_ + l5;
#pragma unroll
            for (int dt = 0; dt < 4; dt++)
                orow[dt * 32] = f2bf(o[dt][r] * iv);
        }
    }
}

extern "C" void kernel_launch(void* const* d_in, const int* in_sizes, int n_in,
                              void* d_out, int out_size, void* d_ws, size_t ws_size,
                              hipStream_t stream)
{
    const float* x  = (const float*)d_in[0];
    const float* Wq = (const float*)d_in[1];
    const float* bq = (const float*)d_in[2];
    const float* Wk = (const float*)d_in[3];
    const float* bk = (const float*)d_in[4];
    const float* Wv = (const float*)d_in[5];
    const float* bv = (const float*)d_in[6];
    const float* Wo = (const float*)d_in[7];
    const float* bo = (const float*)d_in[8];
    const float* fc = (const float*)d_in[9];
    const float* fs = (const float*)d_in[10];
    // d_in[11] (mask): fixed causal mask, analytic. d_in[12] (start_pos): 0.

    const size_t M1 = (size_t)1024 * 1024;
    u16t* ws   = (u16t*)d_ws;
    u16t* x_bf = ws;
    u16t* att  = ws;
    u16t* Wqt  = ws + 16 * M1;
    u16t* Wot  = ws + 16 * M1;
    u16t* Wkt  = ws + 20 * M1;
    u16t* Wvt  = ws + 21 * M1;
    u16t* k_t  = ws + 22 * M1;
    u16t* v_t  = ws + 26 * M1;
    u16t* q_t  = (u16t*)d_out;

    f32_to_bf16<<<dim3(16384), 256, 0, stream>>>(x, x_bf);

    dim3 tb(32, 32);
    transpose_f32_bf16<<<dim3(64, 64), tb, 0, stream>>>(Wq, Wqt, 2048, 2048);
    transpose_f32_bf16<<<dim3(16, 64), tb, 0, stream>>>(Wk, Wkt, 512, 2048);
    transpose_f32_bf16<<<dim3(16, 64), tb, 0, stream>>>(Wv, Wvt, 512, 2048);

    gemm_qkv<<<dim3(24, 64), 256, 0, stream>>>(x_bf, Wqt, bq, bk, bv,
                                               q_t, k_t, v_t, fc, fs);

    attn_kernel<<<dim3(8, 64), 256, 0, stream>>>(q_t, k_t, v_t, att);

    transpose_f32_bf16<<<dim3(64, 64), tb, 0, stream>>>(Wo, Wot, 2048, 2048);

    gemm_o<<<dim3(16, 64), 256, 0, stream>>>(att, Wot, bo, (float*)d_out);
}